// Round 9
// baseline (573.241 us; speedup 1.0000x reference)
//
#include <hip/hip_runtime.h>

constexpr int Bn  = 524288;
constexpr int Cn  = 42;
constexpr int BC  = Bn * Cn;     // 22020096
constexpr int BC4 = BC / 4;      // 5505024
constexpr int QS  = 672;         // q-stride = 16*42 (tile-local mapping, R6)
constexpr int TS  = 4 * QS;      // 2688
constexpr float EPSf = 1e-7f;

constexpr int MLP_BLOCKS = 1344; // 1344 * 16 * 256 == BC4 exactly
constexpr int MLP_ITERS  = 16;

typedef float f4 __attribute__((ext_vector_type(4)));
struct F3 { float x, y, z; };

__device__ __forceinline__ float frcp(float x) { return __builtin_amdgcn_rcpf(x); }

// ---------------- K1: tau reduction, fill-shaped ----------------
// thread t: reads tau[(4t)*8 .. (4t+3)*8+7] = 128 contiguous bytes,
// writes out[4t .. 4t+3] = one float4 (tau_total staged in t_direct slot).
__global__ __launch_bounds__(256) void reduce_kernel(
    const float* __restrict__ tau, float* __restrict__ out)
{
    const long t = blockIdx.x * 256 + threadIdx.x;   // < BC4
    const f4* src = reinterpret_cast<const f4*>(tau) + t * 8;
    f4 r;
#pragma unroll
    for (int q = 0; q < 4; ++q) {
        f4 a = __builtin_nontemporal_load(src + 2 * q);
        f4 b = __builtin_nontemporal_load(src + 2 * q + 1);
        r[q] = ((a.x + a.y) + (a.z + a.w)) + ((b.x + b.y) + (b.z + b.w));
    }
    __builtin_nontemporal_store(r, reinterpret_cast<f4*>(out) + t);
}

// ---------------- K2: persistent MLP + transmittances ----------------
// LDS weight layout (R1-proven, conflict-free): 213 rows x 42 ch, stride 42.
// Rows 0..108   : direct net   (L1: o*10+i, bias o*10+9 | L2: 50+o*6+i,+5 | L3: 74+o*5+i,+4 | L4: 94+o*5+i,+4)
// Rows 109..212 : diffuse net  (L1: 109+o*9+i,+8 | L2: 154+o*6+i,+5 | L3: 178+o*5+i,+4 | L4: 198+o*5+i,+4)
__global__ __launch_bounds__(256) void mlp_kernel(
    const float* __restrict__ mu_direct,
    const float* __restrict__ mu_diffuse,
    const float* __restrict__ cons,
    const float* __restrict__ dW1, const float* __restrict__ db1,
    const float* __restrict__ dW2, const float* __restrict__ db2,
    const float* __restrict__ dW3, const float* __restrict__ db3,
    const float* __restrict__ dW4, const float* __restrict__ db4,
    const float* __restrict__ fW1, const float* __restrict__ fb1,
    const float* __restrict__ fW2, const float* __restrict__ fb2,
    const float* __restrict__ fW3, const float* __restrict__ fb3,
    const float* __restrict__ fW4, const float* __restrict__ fb4,
    float* __restrict__ out)
{
    __shared__ float lds[213 * 42];

    auto stage = [&](const float* __restrict__ src, int n, int per_c, auto rowfn) {
        for (int i = threadIdx.x; i < n; i += 256) {
            int cc  = i / per_c;
            int rem = i - cc * per_c;
            lds[rowfn(rem) * 42 + cc] = src[i];
        }
    };
    stage(dW1, 1890, 45, [](int r) { return (r / 9) * 10 + (r % 9); });
    stage(db1,  210,  5, [](int r) { return r * 10 + 9; });
    stage(dW2,  840, 20, [](int r) { return 50 + (r / 5) * 6 + (r % 5); });
    stage(db2,  168,  4, [](int r) { return 50 + r * 6 + 5; });
    stage(dW3,  672, 16, [](int r) { return 74 + (r / 4) * 5 + (r % 4); });
    stage(db3,  168,  4, [](int r) { return 74 + r * 5 + 4; });
    stage(dW4,  504, 12, [](int r) { return 94 + (r / 4) * 5 + (r % 4); });
    stage(db4,  126,  3, [](int r) { return 94 + r * 5 + 4; });
    stage(fW1, 1680, 40, [](int r) { return 109 + (r / 8) * 9 + (r % 8); });
    stage(fb1,  210,  5, [](int r) { return 109 + r * 9 + 8; });
    stage(fW2,  840, 20, [](int r) { return 154 + (r / 5) * 6 + (r % 5); });
    stage(fb2,  168,  4, [](int r) { return 154 + r * 6 + 5; });
    stage(fW3,  672, 16, [](int r) { return 178 + (r / 4) * 5 + (r % 4); });
    stage(fb3,  168,  4, [](int r) { return 178 + r * 5 + 4; });
    stage(fW4,  504, 12, [](int r) { return 198 + (r / 4) * 5 + (r % 4); });
    stage(fb4,  126,  3, [](int r) { return 198 + r * 5 + 4; });
    __syncthreads();

#pragma unroll 1
    for (int it = 0; it < MLP_ITERS; ++it) {
        const int u    = (blockIdx.x * MLP_ITERS + it) * 256 + threadIdx.x;  // < BC4
        const int tile = u / QS;
        const int lane = u - tile * QS;
        const int p0   = tile * TS + lane;
        const int c    = lane % Cn;
        const int b0   = p0 / Cn;
        const float* wc = lds + c;

        // early: issue tau_total reads (consumed at the end)
        float tt[4];
#pragma unroll
        for (int q = 0; q < 4; ++q) tt[q] = out[p0 + q * QS];

        float mud[4], muf[4], invd[4];
        float xc[4][8];
#pragma unroll
        for (int q = 0; q < 4; ++q) {
            const int bq = b0 + q * 16;
            float md = mu_direct[bq];
            muf[q] = mu_diffuse[bq];
            const f4* c4 = reinterpret_cast<const f4*>(cons) + bq * 2;
            f4 ca = c4[0], cb = c4[1];
            xc[q][0] = ca.x; xc[q][1] = ca.y; xc[q][2] = ca.z; xc[q][3] = ca.w;
            xc[q][4] = cb.x; xc[q][5] = cb.y; xc[q][6] = cb.z; xc[q][7] = cb.w;
            mud[q] = md; invd[q] = frcp(md + EPSf);
        }

        float h1[4][5], h2[4][4], h3[4][4], oo[4][3];

        // ---- diffuse net (raw constituents) ----
#pragma unroll
        for (int o = 0; o < 5; ++o) {
            float a0 = 0.f, a1 = 0.f, a2 = 0.f, a3 = 0.f;
#pragma unroll
            for (int i = 0; i < 8; ++i) {
                float w = wc[(109 + o * 9 + i) * 42];
                a0 = fmaf(w, xc[0][i], a0);
                a1 = fmaf(w, xc[1][i], a1);
                a2 = fmaf(w, xc[2][i], a2);
                a3 = fmaf(w, xc[3][i], a3);
            }
            float bs = wc[(109 + o * 9 + 8) * 42];
            h1[0][o] = fmaxf(a0 + bs, 0.f);
            h1[1][o] = fmaxf(a1 + bs, 0.f);
            h1[2][o] = fmaxf(a2 + bs, 0.f);
            h1[3][o] = fmaxf(a3 + bs, 0.f);
        }
#pragma unroll
        for (int o = 0; o < 4; ++o) {
            float a0 = 0.f, a1 = 0.f, a2 = 0.f, a3 = 0.f;
#pragma unroll
            for (int i = 0; i < 5; ++i) {
                float w = wc[(154 + o * 6 + i) * 42];
                a0 = fmaf(w, h1[0][i], a0);
                a1 = fmaf(w, h1[1][i], a1);
                a2 = fmaf(w, h1[2][i], a2);
                a3 = fmaf(w, h1[3][i], a3);
            }
            float bs = wc[(154 + o * 6 + 5) * 42];
            h2[0][o] = fmaxf(a0 + bs, 0.f);
            h2[1][o] = fmaxf(a1 + bs, 0.f);
            h2[2][o] = fmaxf(a2 + bs, 0.f);
            h2[3][o] = fmaxf(a3 + bs, 0.f);
        }
#pragma unroll
        for (int o = 0; o < 4; ++o) {
            float a0 = 0.f, a1 = 0.f, a2 = 0.f, a3 = 0.f;
#pragma unroll
            for (int i = 0; i < 4; ++i) {
                float w = wc[(178 + o * 5 + i) * 42];
                a0 = fmaf(w, h2[0][i], a0);
                a1 = fmaf(w, h2[1][i], a1);
                a2 = fmaf(w, h2[2][i], a2);
                a3 = fmaf(w, h2[3][i], a3);
            }
            float bs = wc[(178 + o * 5 + 4) * 42];
            h3[0][o] = fmaxf(a0 + bs, 0.f);
            h3[1][o] = fmaxf(a1 + bs, 0.f);
            h3[2][o] = fmaxf(a2 + bs, 0.f);
            h3[3][o] = fmaxf(a3 + bs, 0.f);
        }
#pragma unroll
        for (int o = 0; o < 3; ++o) {
            float a0 = 0.f, a1 = 0.f, a2 = 0.f, a3 = 0.f;
#pragma unroll
            for (int i = 0; i < 4; ++i) {
                float w = wc[(198 + o * 5 + i) * 42];
                a0 = fmaf(w, h3[0][i], a0);
                a1 = fmaf(w, h3[1][i], a1);
                a2 = fmaf(w, h3[2][i], a2);
                a3 = fmaf(w, h3[3][i], a3);
            }
            float bs = wc[(198 + o * 5 + 4) * 42];
            oo[0][o] = a0 + bs; oo[1][o] = a1 + bs; oo[2][o] = a2 + bs; oo[3][o] = a3 + bs;
        }
#pragma unroll
        for (int q = 0; q < 4; ++q) {
            float v0 = oo[q][0], v1 = oo[q][1], v2 = oo[q][2];
            float m = fmaxf(fmaxf(v0, v1), v2);
            float e0 = __expf(v0 - m), e1 = __expf(v1 - m), e2 = __expf(v2 - m);
            float rs = frcp(e0 + e1 + e2);
            F3 v; v.x = e0 * rs; v.y = e1 * rs; v.z = e2 * rs;
            *reinterpret_cast<F3*>(out + 5 * BC + (p0 + q * QS) * 3) = v;
        }

        // ---- direct net ([cons/(mu_d+eps), mu_d]) ----
#pragma unroll
        for (int q = 0; q < 4; ++q)
#pragma unroll
            for (int i = 0; i < 8; ++i) xc[q][i] *= invd[q];

#pragma unroll
        for (int o = 0; o < 5; ++o) {
            float a0 = 0.f, a1 = 0.f, a2 = 0.f, a3 = 0.f;
#pragma unroll
            for (int i = 0; i < 9; ++i) {
                float w = wc[(o * 10 + i) * 42];
                float x0 = (i < 8) ? xc[0][i] : mud[0];
                float x1 = (i < 8) ? xc[1][i] : mud[1];
                float x2 = (i < 8) ? xc[2][i] : mud[2];
                float x3 = (i < 8) ? xc[3][i] : mud[3];
                a0 = fmaf(w, x0, a0);
                a1 = fmaf(w, x1, a1);
                a2 = fmaf(w, x2, a2);
                a3 = fmaf(w, x3, a3);
            }
            float bs = wc[(o * 10 + 9) * 42];
            h1[0][o] = fmaxf(a0 + bs, 0.f);
            h1[1][o] = fmaxf(a1 + bs, 0.f);
            h1[2][o] = fmaxf(a2 + bs, 0.f);
            h1[3][o] = fmaxf(a3 + bs, 0.f);
        }
#pragma unroll
        for (int o = 0; o < 4; ++o) {
            float a0 = 0.f, a1 = 0.f, a2 = 0.f, a3 = 0.f;
#pragma unroll
            for (int i = 0; i < 5; ++i) {
                float w = wc[(50 + o * 6 + i) * 42];
                a0 = fmaf(w, h1[0][i], a0);
                a1 = fmaf(w, h1[1][i], a1);
                a2 = fmaf(w, h1[2][i], a2);
                a3 = fmaf(w, h1[3][i], a3);
            }
            float bs = wc[(50 + o * 6 + 5) * 42];
            h2[0][o] = fmaxf(a0 + bs, 0.f);
            h2[1][o] = fmaxf(a1 + bs, 0.f);
            h2[2][o] = fmaxf(a2 + bs, 0.f);
            h2[3][o] = fmaxf(a3 + bs, 0.f);
        }
#pragma unroll
        for (int o = 0; o < 4; ++o) {
            float a0 = 0.f, a1 = 0.f, a2 = 0.f, a3 = 0.f;
#pragma unroll
            for (int i = 0; i < 4; ++i) {
                float w = wc[(74 + o * 5 + i) * 42];
                a0 = fmaf(w, h2[0][i], a0);
                a1 = fmaf(w, h2[1][i], a1);
                a2 = fmaf(w, h2[2][i], a2);
                a3 = fmaf(w, h2[3][i], a3);
            }
            float bs = wc[(74 + o * 5 + 4) * 42];
            h3[0][o] = fmaxf(a0 + bs, 0.f);
            h3[1][o] = fmaxf(a1 + bs, 0.f);
            h3[2][o] = fmaxf(a2 + bs, 0.f);
            h3[3][o] = fmaxf(a3 + bs, 0.f);
        }
#pragma unroll
        for (int o = 0; o < 3; ++o) {
            float a0 = 0.f, a1 = 0.f, a2 = 0.f, a3 = 0.f;
#pragma unroll
            for (int i = 0; i < 4; ++i) {
                float w = wc[(94 + o * 5 + i) * 42];
                a0 = fmaf(w, h3[0][i], a0);
                a1 = fmaf(w, h3[1][i], a1);
                a2 = fmaf(w, h3[2][i], a2);
                a3 = fmaf(w, h3[3][i], a3);
            }
            float bs = wc[(94 + o * 5 + 4) * 42];
            oo[0][o] = a0 + bs; oo[1][o] = a1 + bs; oo[2][o] = a2 + bs; oo[3][o] = a3 + bs;
        }
#pragma unroll
        for (int q = 0; q < 4; ++q) {
            float v0 = oo[q][0], v1 = oo[q][1], v2 = oo[q][2];
            float m = fmaxf(fmaxf(v0, v1), v2);
            float e0 = __expf(v0 - m), e1 = __expf(v1 - m), e2 = __expf(v2 - m);
            float rs = frcp(e0 + e1 + e2);
            F3 v; v.x = e0 * rs; v.y = e1 * rs; v.z = e2 * rs;
            *reinterpret_cast<F3*>(out + 2 * BC + (p0 + q * QS) * 3) = v;
        }

        // ---- transmittances: consume tau_total, overwrite in place ----
#pragma unroll
        for (int q = 0; q < 4; ++q) {
            const int pq = p0 + q * QS;
            out[pq]      = __expf(-tt[q] * invd[q]);
            out[BC + pq] = __expf(-tt[q] * frcp(muf[q] + EPSf));
        }
    }
}

extern "C" void kernel_launch(void* const* d_in, const int* in_sizes, int n_in,
                              void* d_out, int out_size, void* d_ws, size_t ws_size,
                              hipStream_t stream) {
    const float* tau  = (const float*)d_in[0];
    const float* mu_d = (const float*)d_in[1];
    const float* mu_f = (const float*)d_in[2];
    const float* cons = (const float*)d_in[3];

    reduce_kernel<<<dim3(BC4 / 256), 256, 0, stream>>>(tau, (float*)d_out);

    mlp_kernel<<<dim3(MLP_BLOCKS), 256, 0, stream>>>(
        mu_d, mu_f, cons,
        (const float*)d_in[4],  (const float*)d_in[5],
        (const float*)d_in[6],  (const float*)d_in[7],
        (const float*)d_in[8],  (const float*)d_in[9],
        (const float*)d_in[10], (const float*)d_in[11],
        (const float*)d_in[12], (const float*)d_in[13],
        (const float*)d_in[14], (const float*)d_in[15],
        (const float*)d_in[16], (const float*)d_in[17],
        (const float*)d_in[18], (const float*)d_in[19],
        (float*)d_out);
}

// Round 10
// 438.999 us; speedup vs baseline: 1.3058x; 1.3058x over previous
//
#include <hip/hip_runtime.h>
#include <stdint.h>

constexpr int Bn  = 524288;
constexpr int Cn  = 42;
constexpr int BC  = Bn * Cn;     // 22020096
constexpr int BC4 = BC / 4;      // 5505024
constexpr int QS  = 672;
constexpr int TS  = 4 * QS;
constexpr float EPSf = 1e-7f;

constexpr int TRB = 1024;        // trans blocks
constexpr int TRI = 42;          // trans iters/block; 1024*4*42*128 == BC exactly
constexpr int MLP_BLOCKS = 1344; // 1344*16*256 == BC4 exactly
constexpr int MLP_ITERS  = 16;

typedef float f4 __attribute__((ext_vector_type(4)));
struct F3 { float x, y, z; };
typedef __attribute__((address_space(3))) uint32_t lds32;
typedef __attribute__((address_space(1))) const uint32_t gbl32;

__device__ __forceinline__ float frcp(float x) { return __builtin_amdgcn_rcpf(x); }

// ---------------- K_trans: deep-pipelined tau reduction via global_load_lds ----------------
// Per wave: private 2x4KB LDS double buffer, 128 p's per iter (p_lo=ch+lane, p_hi=ch+64+lane).
// Staged 4-element-group transposed: LDS[k*256+4*lane+j] = tau[(ch+(k&1)*64+lane)*8+(k>>1)*4+j]
// -> consume is one ds_read_b128 per half-p. No barriers anywhere (no cross-wave sharing).
__global__ __launch_bounds__(256) void trans_kernel(
    const float* __restrict__ tau,
    const float* __restrict__ mu_direct,
    const float* __restrict__ mu_diffuse,
    float* __restrict__ out)
{
    __shared__ float sbuf[4][2][1024];   // [wave][buf][4KB]
    const int wid  = threadIdx.x >> 6;
    const int lane = threadIdx.x & 63;

    auto chunkof = [&](int j) { return ((blockIdx.x * TRI + j) * 4 + wid) * 128; };

    auto stage = [&](int j, int b) {
        const int ch = chunkof(j);
#pragma unroll
        for (int k = 0; k < 4; ++k) {
            const float* src = tau + (size_t)(ch + (k & 1) * 64 + lane) * 8 + (k >> 1) * 4;
            __builtin_amdgcn_global_load_lds((gbl32*)src, (lds32*)&sbuf[wid][b][k * 256], 16, 0, 0);
        }
    };

    stage(0, 0);
#pragma unroll 1
    for (int j = 0; j < TRI; ++j) {
        const int ch  = chunkof(j);
        const int plo = ch + lane, phi = ch + 64 + lane;
        // consume mu early (its wait also drains stage(j), issued last iter -> already landed)
        const int blo = plo / Cn, bhi = phi / Cn;
        float rdlo = frcp(mu_direct[blo] + EPSf), rflo = frcp(mu_diffuse[blo] + EPSf);
        float rdhi = frcp(mu_direct[bhi] + EPSf), rfhi = frcp(mu_diffuse[bhi] + EPSf);
        // prefetch next chunk into other buffer; stays in flight across the consume phase
        if (j + 1 < TRI) {
            stage(j + 1, (j + 1) & 1);
            asm volatile("s_waitcnt vmcnt(4)" ::: "memory");
        } else {
            asm volatile("s_waitcnt vmcnt(0)" ::: "memory");
        }
        const float* bb = &sbuf[wid][j & 1][0];
        f4 a0 = *(const f4*)(bb + 4 * lane);
        f4 a1 = *(const f4*)(bb + 512 + 4 * lane);
        f4 b0 = *(const f4*)(bb + 256 + 4 * lane);
        f4 b1 = *(const f4*)(bb + 768 + 4 * lane);
        float tlo = ((a0.x + a0.y) + (a0.z + a0.w)) + ((a1.x + a1.y) + (a1.z + a1.w));
        float thi = ((b0.x + b0.y) + (b0.z + b0.w)) + ((b1.x + b1.y) + (b1.z + b1.w));
        out[plo]      = __expf(-tlo * rdlo);
        out[BC + plo] = __expf(-tlo * rflo);
        out[phi]      = __expf(-thi * rdhi);
        out[BC + phi] = __expf(-thi * rfhi);
    }
}

// ---------------- K_mlp: persistent MLP (R7-proven), e_split outputs only ----------------
// LDS weight layout: 213 rows x 42 ch, stride 42 (conflict-free).
__global__ __launch_bounds__(256) void mlp_kernel(
    const float* __restrict__ mu_direct,
    const float* __restrict__ cons,
    const float* __restrict__ dW1, const float* __restrict__ db1,
    const float* __restrict__ dW2, const float* __restrict__ db2,
    const float* __restrict__ dW3, const float* __restrict__ db3,
    const float* __restrict__ dW4, const float* __restrict__ db4,
    const float* __restrict__ fW1, const float* __restrict__ fb1,
    const float* __restrict__ fW2, const float* __restrict__ fb2,
    const float* __restrict__ fW3, const float* __restrict__ fb3,
    const float* __restrict__ fW4, const float* __restrict__ fb4,
    float* __restrict__ out)
{
    __shared__ float lds[213 * 42];

    auto stage = [&](const float* __restrict__ src, int n, int per_c, auto rowfn) {
        for (int i = threadIdx.x; i < n; i += 256) {
            int cc  = i / per_c;
            int rem = i - cc * per_c;
            lds[rowfn(rem) * 42 + cc] = src[i];
        }
    };
    stage(dW1, 1890, 45, [](int r) { return (r / 9) * 10 + (r % 9); });
    stage(db1,  210,  5, [](int r) { return r * 10 + 9; });
    stage(dW2,  840, 20, [](int r) { return 50 + (r / 5) * 6 + (r % 5); });
    stage(db2,  168,  4, [](int r) { return 50 + r * 6 + 5; });
    stage(dW3,  672, 16, [](int r) { return 74 + (r / 4) * 5 + (r % 4); });
    stage(db3,  168,  4, [](int r) { return 74 + r * 5 + 4; });
    stage(dW4,  504, 12, [](int r) { return 94 + (r / 4) * 5 + (r % 4); });
    stage(db4,  126,  3, [](int r) { return 94 + r * 5 + 4; });
    stage(fW1, 1680, 40, [](int r) { return 109 + (r / 8) * 9 + (r % 8); });
    stage(fb1,  210,  5, [](int r) { return 109 + r * 9 + 8; });
    stage(fW2,  840, 20, [](int r) { return 154 + (r / 5) * 6 + (r % 5); });
    stage(fb2,  168,  4, [](int r) { return 154 + r * 6 + 5; });
    stage(fW3,  672, 16, [](int r) { return 178 + (r / 4) * 5 + (r % 4); });
    stage(fb3,  168,  4, [](int r) { return 178 + r * 5 + 4; });
    stage(fW4,  504, 12, [](int r) { return 198 + (r / 4) * 5 + (r % 4); });
    stage(fb4,  126,  3, [](int r) { return 198 + r * 5 + 4; });
    __syncthreads();

#pragma unroll 1
    for (int it = 0; it < MLP_ITERS; ++it) {
        const int u    = (blockIdx.x * MLP_ITERS + it) * 256 + threadIdx.x;  // < BC4
        const int tile = u / QS;
        const int lane = u - tile * QS;
        const int p0   = tile * TS + lane;
        const int c    = lane % Cn;
        const int b0   = p0 / Cn;
        const float* wc = lds + c;

        float mud[4], invd[4];
        float xc[4][8];
#pragma unroll
        for (int q = 0; q < 4; ++q) {
            const int bq = b0 + q * 16;
            float md = mu_direct[bq];
            const f4* c4 = reinterpret_cast<const f4*>(cons) + bq * 2;
            f4 ca = c4[0], cb = c4[1];
            xc[q][0] = ca.x; xc[q][1] = ca.y; xc[q][2] = ca.z; xc[q][3] = ca.w;
            xc[q][4] = cb.x; xc[q][5] = cb.y; xc[q][6] = cb.z; xc[q][7] = cb.w;
            mud[q] = md; invd[q] = frcp(md + EPSf);
        }

        float h1[4][5], h2[4][4], h3[4][4], oo[4][3];

        // ---- diffuse net (raw constituents) ----
#pragma unroll
        for (int o = 0; o < 5; ++o) {
            float a0 = 0.f, a1 = 0.f, a2 = 0.f, a3 = 0.f;
#pragma unroll
            for (int i = 0; i < 8; ++i) {
                float w = wc[(109 + o * 9 + i) * 42];
                a0 = fmaf(w, xc[0][i], a0);
                a1 = fmaf(w, xc[1][i], a1);
                a2 = fmaf(w, xc[2][i], a2);
                a3 = fmaf(w, xc[3][i], a3);
            }
            float bs = wc[(109 + o * 9 + 8) * 42];
            h1[0][o] = fmaxf(a0 + bs, 0.f);
            h1[1][o] = fmaxf(a1 + bs, 0.f);
            h1[2][o] = fmaxf(a2 + bs, 0.f);
            h1[3][o] = fmaxf(a3 + bs, 0.f);
        }
#pragma unroll
        for (int o = 0; o < 4; ++o) {
            float a0 = 0.f, a1 = 0.f, a2 = 0.f, a3 = 0.f;
#pragma unroll
            for (int i = 0; i < 5; ++i) {
                float w = wc[(154 + o * 6 + i) * 42];
                a0 = fmaf(w, h1[0][i], a0);
                a1 = fmaf(w, h1[1][i], a1);
                a2 = fmaf(w, h1[2][i], a2);
                a3 = fmaf(w, h1[3][i], a3);
            }
            float bs = wc[(154 + o * 6 + 5) * 42];
            h2[0][o] = fmaxf(a0 + bs, 0.f);
            h2[1][o] = fmaxf(a1 + bs, 0.f);
            h2[2][o] = fmaxf(a2 + bs, 0.f);
            h2[3][o] = fmaxf(a3 + bs, 0.f);
        }
#pragma unroll
        for (int o = 0; o < 4; ++o) {
            float a0 = 0.f, a1 = 0.f, a2 = 0.f, a3 = 0.f;
#pragma unroll
            for (int i = 0; i < 4; ++i) {
                float w = wc[(178 + o * 5 + i) * 42];
                a0 = fmaf(w, h2[0][i], a0);
                a1 = fmaf(w, h2[1][i], a1);
                a2 = fmaf(w, h2[2][i], a2);
                a3 = fmaf(w, h2[3][i], a3);
            }
            float bs = wc[(178 + o * 5 + 4) * 42];
            h3[0][o] = fmaxf(a0 + bs, 0.f);
            h3[1][o] = fmaxf(a1 + bs, 0.f);
            h3[2][o] = fmaxf(a2 + bs, 0.f);
            h3[3][o] = fmaxf(a3 + bs, 0.f);
        }
#pragma unroll
        for (int o = 0; o < 3; ++o) {
            float a0 = 0.f, a1 = 0.f, a2 = 0.f, a3 = 0.f;
#pragma unroll
            for (int i = 0; i < 4; ++i) {
                float w = wc[(198 + o * 5 + i) * 42];
                a0 = fmaf(w, h3[0][i], a0);
                a1 = fmaf(w, h3[1][i], a1);
                a2 = fmaf(w, h3[2][i], a2);
                a3 = fmaf(w, h3[3][i], a3);
            }
            float bs = wc[(198 + o * 5 + 4) * 42];
            oo[0][o] = a0 + bs; oo[1][o] = a1 + bs; oo[2][o] = a2 + bs; oo[3][o] = a3 + bs;
        }
#pragma unroll
        for (int q = 0; q < 4; ++q) {
            float v0 = oo[q][0], v1 = oo[q][1], v2 = oo[q][2];
            float m = fmaxf(fmaxf(v0, v1), v2);
            float e0 = __expf(v0 - m), e1 = __expf(v1 - m), e2 = __expf(v2 - m);
            float rs = frcp(e0 + e1 + e2);
            F3 v; v.x = e0 * rs; v.y = e1 * rs; v.z = e2 * rs;
            *reinterpret_cast<F3*>(out + 5 * BC + (p0 + q * QS) * 3) = v;
        }

        // ---- direct net ([cons/(mu_d+eps), mu_d]) ----
#pragma unroll
        for (int q = 0; q < 4; ++q)
#pragma unroll
            for (int i = 0; i < 8; ++i) xc[q][i] *= invd[q];

#pragma unroll
        for (int o = 0; o < 5; ++o) {
            float a0 = 0.f, a1 = 0.f, a2 = 0.f, a3 = 0.f;
#pragma unroll
            for (int i = 0; i < 9; ++i) {
                float w = wc[(o * 10 + i) * 42];
                float x0 = (i < 8) ? xc[0][i] : mud[0];
                float x1 = (i < 8) ? xc[1][i] : mud[1];
                float x2 = (i < 8) ? xc[2][i] : mud[2];
                float x3 = (i < 8) ? xc[3][i] : mud[3];
                a0 = fmaf(w, x0, a0);
                a1 = fmaf(w, x1, a1);
                a2 = fmaf(w, x2, a2);
                a3 = fmaf(w, x3, a3);
            }
            float bs = wc[(o * 10 + 9) * 42];
            h1[0][o] = fmaxf(a0 + bs, 0.f);
            h1[1][o] = fmaxf(a1 + bs, 0.f);
            h1[2][o] = fmaxf(a2 + bs, 0.f);
            h1[3][o] = fmaxf(a3 + bs, 0.f);
        }
#pragma unroll
        for (int o = 0; o < 4; ++o) {
            float a0 = 0.f, a1 = 0.f, a2 = 0.f, a3 = 0.f;
#pragma unroll
            for (int i = 0; i < 5; ++i) {
                float w = wc[(50 + o * 6 + i) * 42];
                a0 = fmaf(w, h1[0][i], a0);
                a1 = fmaf(w, h1[1][i], a1);
                a2 = fmaf(w, h1[2][i], a2);
                a3 = fmaf(w, h1[3][i], a3);
            }
            float bs = wc[(50 + o * 6 + 5) * 42];
            h2[0][o] = fmaxf(a0 + bs, 0.f);
            h2[1][o] = fmaxf(a1 + bs, 0.f);
            h2[2][o] = fmaxf(a2 + bs, 0.f);
            h2[3][o] = fmaxf(a3 + bs, 0.f);
        }
#pragma unroll
        for (int o = 0; o < 4; ++o) {
            float a0 = 0.f, a1 = 0.f, a2 = 0.f, a3 = 0.f;
#pragma unroll
            for (int i = 0; i < 4; ++i) {
                float w = wc[(74 + o * 5 + i) * 42];
                a0 = fmaf(w, h2[0][i], a0);
                a1 = fmaf(w, h2[1][i], a1);
                a2 = fmaf(w, h2[2][i], a2);
                a3 = fmaf(w, h2[3][i], a3);
            }
            float bs = wc[(74 + o * 5 + 4) * 42];
            h3[0][o] = fmaxf(a0 + bs, 0.f);
            h3[1][o] = fmaxf(a1 + bs, 0.f);
            h3[2][o] = fmaxf(a2 + bs, 0.f);
            h3[3][o] = fmaxf(a3 + bs, 0.f);
        }
#pragma unroll
        for (int o = 0; o < 3; ++o) {
            float a0 = 0.f, a1 = 0.f, a2 = 0.f, a3 = 0.f;
#pragma unroll
            for (int i = 0; i < 4; ++i) {
                float w = wc[(94 + o * 5 + i) * 42];
                a0 = fmaf(w, h3[0][i], a0);
                a1 = fmaf(w, h3[1][i], a1);
                a2 = fmaf(w, h3[2][i], a2);
                a3 = fmaf(w, h3[3][i], a3);
            }
            float bs = wc[(94 + o * 5 + 4) * 42];
            oo[0][o] = a0 + bs; oo[1][o] = a1 + bs; oo[2][o] = a2 + bs; oo[3][o] = a3 + bs;
        }
#pragma unroll
        for (int q = 0; q < 4; ++q) {
            float v0 = oo[q][0], v1 = oo[q][1], v2 = oo[q][2];
            float m = fmaxf(fmaxf(v0, v1), v2);
            float e0 = __expf(v0 - m), e1 = __expf(v1 - m), e2 = __expf(v2 - m);
            float rs = frcp(e0 + e1 + e2);
            F3 v; v.x = e0 * rs; v.y = e1 * rs; v.z = e2 * rs;
            *reinterpret_cast<F3*>(out + 2 * BC + (p0 + q * QS) * 3) = v;
        }
    }
}

extern "C" void kernel_launch(void* const* d_in, const int* in_sizes, int n_in,
                              void* d_out, int out_size, void* d_ws, size_t ws_size,
                              hipStream_t stream) {
    const float* tau  = (const float*)d_in[0];
    const float* mu_d = (const float*)d_in[1];
    const float* mu_f = (const float*)d_in[2];
    const float* cons = (const float*)d_in[3];

    trans_kernel<<<dim3(TRB), 256, 0, stream>>>(tau, mu_d, mu_f, (float*)d_out);

    mlp_kernel<<<dim3(MLP_BLOCKS), 256, 0, stream>>>(
        mu_d, cons,
        (const float*)d_in[4],  (const float*)d_in[5],
        (const float*)d_in[6],  (const float*)d_in[7],
        (const float*)d_in[8],  (const float*)d_in[9],
        (const float*)d_in[10], (const float*)d_in[11],
        (const float*)d_in[12], (const float*)d_in[13],
        (const float*)d_in[14], (const float*)d_in[15],
        (const float*)d_in[16], (const float*)d_in[17],
        (const float*)d_in[18], (const float*)d_in[19],
        (float*)d_out);
}

// Round 11
// 348.962 us; speedup vs baseline: 1.6427x; 1.2580x over previous
//
#include <hip/hip_runtime.h>

constexpr int Bn  = 524288;
constexpr int Cn  = 42;
constexpr int BC  = Bn * Cn;     // 22020096
constexpr int BC4 = BC / 4;      // 5505024 threads, each does 4 outputs
constexpr int QS  = 672;         // q-stride = 16*42: c preserved, b += 16
constexpr int TS  = 4 * QS;      // tile span = 2688 p's; BC / TS = 8192 tiles exactly
constexpr float EPSf = 1e-7f;

typedef float f4 __attribute__((ext_vector_type(4)));

__device__ __forceinline__ float frcp(float x) { return __builtin_amdgcn_rcpf(x); }

// LDS weight layout (R1-proven, conflict-free): 213 rows x 42 ch, stride 42.
// Rows 0..108   : direct net   (L1: o*10+i, bias o*10+9 | L2: 50+o*6+i,+5 | L3: 74+o*5+i,+4 | L4: 94+o*5+i,+4)
// Rows 109..212 : diffuse net  (L1: 109+o*9+i,+8 | L2: 154+o*6+i,+5 | L3: 178+o*5+i,+4 | L4: 198+o*5+i,+4)

__global__ __launch_bounds__(256) void scat_main(
    const float* __restrict__ tau,
    const float* __restrict__ mu_direct,
    const float* __restrict__ mu_diffuse,
    const float* __restrict__ cons,
    const float* __restrict__ dW1, const float* __restrict__ db1,
    const float* __restrict__ dW2, const float* __restrict__ db2,
    const float* __restrict__ dW3, const float* __restrict__ db3,
    const float* __restrict__ dW4, const float* __restrict__ db4,
    const float* __restrict__ fW1, const float* __restrict__ fb1,
    const float* __restrict__ fW2, const float* __restrict__ fb2,
    const float* __restrict__ fW3, const float* __restrict__ fb3,
    const float* __restrict__ fW4, const float* __restrict__ fb4,
    float* __restrict__ out)
{
    __shared__ float lds[213 * 42];

    auto stage = [&](const float* __restrict__ src, int n, int per_c, auto rowfn) {
        for (int i = threadIdx.x; i < n; i += 256) {
            int cc  = i / per_c;
            int rem = i - cc * per_c;
            lds[rowfn(rem) * 42 + cc] = src[i];
        }
    };
    // direct net
    stage(dW1, 1890, 45, [](int r) { return (r / 9) * 10 + (r % 9); });
    stage(db1,  210,  5, [](int r) { return r * 10 + 9; });
    stage(dW2,  840, 20, [](int r) { return 50 + (r / 5) * 6 + (r % 5); });
    stage(db2,  168,  4, [](int r) { return 50 + r * 6 + 5; });
    stage(dW3,  672, 16, [](int r) { return 74 + (r / 4) * 5 + (r % 4); });
    stage(db3,  168,  4, [](int r) { return 74 + r * 5 + 4; });
    stage(dW4,  504, 12, [](int r) { return 94 + (r / 4) * 5 + (r % 4); });
    stage(db4,  126,  3, [](int r) { return 94 + r * 5 + 4; });
    // diffuse net
    stage(fW1, 1680, 40, [](int r) { return 109 + (r / 8) * 9 + (r % 8); });
    stage(fb1,  210,  5, [](int r) { return 109 + r * 9 + 8; });
    stage(fW2,  840, 20, [](int r) { return 154 + (r / 5) * 6 + (r % 5); });
    stage(fb2,  168,  4, [](int r) { return 154 + r * 6 + 5; });
    stage(fW3,  672, 16, [](int r) { return 178 + (r / 4) * 5 + (r % 4); });
    stage(fb3,  168,  4, [](int r) { return 178 + r * 5 + 4; });
    stage(fW4,  504, 12, [](int r) { return 198 + (r / 4) * 5 + (r % 4); });
    stage(fb4,  126,  3, [](int r) { return 198 + r * 5 + 4; });
    __syncthreads();

    // tile-compact mapping: u -> tile of 2688 p's; thread owns p0 + q*672.
    const int u    = blockIdx.x * 256 + threadIdx.x;   // < BC4
    const int tile = u / QS;
    const int lane = u - tile * QS;
    const int p0   = tile * TS + lane;
    const int c    = lane % Cn;          // TS, QS are multiples of 42
    const int b0   = p0 / Cn;            // b for q: b0 + 16*q
    const float* wc = lds + c;           // row r at wc[r*42]

    float mud[4], invd[4];
    float xc[4][8];

    // tau reduction + transmittances + input loads
#pragma unroll
    for (int q = 0; q < 4; ++q) {
        const int pq = p0 + q * QS;
        const f4* t4 = reinterpret_cast<const f4*>(tau) + pq * 2;
        f4 ta = t4[0], tb = t4[1];
        float tt = ((ta.x + ta.y) + (ta.z + ta.w)) + ((tb.x + tb.y) + (tb.z + tb.w));
        const int bq = b0 + q * 16;
        float md = mu_direct[bq];
        float mf = mu_diffuse[bq];
        const f4* c4 = reinterpret_cast<const f4*>(cons) + bq * 2;
        f4 ca = c4[0], cb = c4[1];
        xc[q][0] = ca.x; xc[q][1] = ca.y; xc[q][2] = ca.z; xc[q][3] = ca.w;
        xc[q][4] = cb.x; xc[q][5] = cb.y; xc[q][6] = cb.z; xc[q][7] = cb.w;
        float id = frcp(md + EPSf);
        float iff = frcp(mf + EPSf);
        out[pq]      = __expf(-tt * id);
        out[BC + pq] = __expf(-tt * iff);
        mud[q] = md; invd[q] = id;
    }

    float h1[4][5], h2[4][4], h3[4][4], oo[4][3];

    // ---------------- diffuse net (input: raw constituents) ----------------
#pragma unroll
    for (int o = 0; o < 5; ++o) {
        float a0 = 0.f, a1 = 0.f, a2 = 0.f, a3 = 0.f;
#pragma unroll
        for (int i = 0; i < 8; ++i) {
            float w = wc[(109 + o * 9 + i) * 42];
            a0 = fmaf(w, xc[0][i], a0);
            a1 = fmaf(w, xc[1][i], a1);
            a2 = fmaf(w, xc[2][i], a2);
            a3 = fmaf(w, xc[3][i], a3);
        }
        float bs = wc[(109 + o * 9 + 8) * 42];
        h1[0][o] = fmaxf(a0 + bs, 0.f);
        h1[1][o] = fmaxf(a1 + bs, 0.f);
        h1[2][o] = fmaxf(a2 + bs, 0.f);
        h1[3][o] = fmaxf(a3 + bs, 0.f);
    }
#pragma unroll
    for (int o = 0; o < 4; ++o) {
        float a0 = 0.f, a1 = 0.f, a2 = 0.f, a3 = 0.f;
#pragma unroll
        for (int i = 0; i < 5; ++i) {
            float w = wc[(154 + o * 6 + i) * 42];
            a0 = fmaf(w, h1[0][i], a0);
            a1 = fmaf(w, h1[1][i], a1);
            a2 = fmaf(w, h1[2][i], a2);
            a3 = fmaf(w, h1[3][i], a3);
        }
        float bs = wc[(154 + o * 6 + 5) * 42];
        h2[0][o] = fmaxf(a0 + bs, 0.f);
        h2[1][o] = fmaxf(a1 + bs, 0.f);
        h2[2][o] = fmaxf(a2 + bs, 0.f);
        h2[3][o] = fmaxf(a3 + bs, 0.f);
    }
#pragma unroll
    for (int o = 0; o < 4; ++o) {
        float a0 = 0.f, a1 = 0.f, a2 = 0.f, a3 = 0.f;
#pragma unroll
        for (int i = 0; i < 4; ++i) {
            float w = wc[(178 + o * 5 + i) * 42];
            a0 = fmaf(w, h2[0][i], a0);
            a1 = fmaf(w, h2[1][i], a1);
            a2 = fmaf(w, h2[2][i], a2);
            a3 = fmaf(w, h2[3][i], a3);
        }
        float bs = wc[(178 + o * 5 + 4) * 42];
        h3[0][o] = fmaxf(a0 + bs, 0.f);
        h3[1][o] = fmaxf(a1 + bs, 0.f);
        h3[2][o] = fmaxf(a2 + bs, 0.f);
        h3[3][o] = fmaxf(a3 + bs, 0.f);
    }
#pragma unroll
    for (int o = 0; o < 3; ++o) {
        float a0 = 0.f, a1 = 0.f, a2 = 0.f, a3 = 0.f;
#pragma unroll
        for (int i = 0; i < 4; ++i) {
            float w = wc[(198 + o * 5 + i) * 42];
            a0 = fmaf(w, h3[0][i], a0);
            a1 = fmaf(w, h3[1][i], a1);
            a2 = fmaf(w, h3[2][i], a2);
            a3 = fmaf(w, h3[3][i], a3);
        }
        float bs = wc[(198 + o * 5 + 4) * 42];
        oo[0][o] = a0 + bs; oo[1][o] = a1 + bs; oo[2][o] = a2 + bs; oo[3][o] = a3 + bs;
    }
#pragma unroll
    for (int q = 0; q < 4; ++q) {
        float v0 = oo[q][0], v1 = oo[q][1], v2 = oo[q][2];
        float m = fmaxf(fmaxf(v0, v1), v2);
        float e0 = __expf(v0 - m), e1 = __expf(v1 - m), e2 = __expf(v2 - m);
        float rs = frcp(e0 + e1 + e2);
        int base = 5 * BC + (p0 + q * QS) * 3;
        out[base + 0] = e0 * rs;
        out[base + 1] = e1 * rs;
        out[base + 2] = e2 * rs;
    }

    // ---------------- direct net (input: [cons/(mu_d+eps), mu_d]) ----------------
#pragma unroll
    for (int q = 0; q < 4; ++q)
#pragma unroll
        for (int i = 0; i < 8; ++i) xc[q][i] *= invd[q];

#pragma unroll
    for (int o = 0; o < 5; ++o) {
        float a0 = 0.f, a1 = 0.f, a2 = 0.f, a3 = 0.f;
#pragma unroll
        for (int i = 0; i < 9; ++i) {
            float w = wc[(o * 10 + i) * 42];
            float x0 = (i < 8) ? xc[0][i] : mud[0];
            float x1 = (i < 8) ? xc[1][i] : mud[1];
            float x2 = (i < 8) ? xc[2][i] : mud[2];
            float x3 = (i < 8) ? xc[3][i] : mud[3];
            a0 = fmaf(w, x0, a0);
            a1 = fmaf(w, x1, a1);
            a2 = fmaf(w, x2, a2);
            a3 = fmaf(w, x3, a3);
        }
        float bs = wc[(o * 10 + 9) * 42];
        h1[0][o] = fmaxf(a0 + bs, 0.f);
        h1[1][o] = fmaxf(a1 + bs, 0.f);
        h1[2][o] = fmaxf(a2 + bs, 0.f);
        h1[3][o] = fmaxf(a3 + bs, 0.f);
    }
#pragma unroll
    for (int o = 0; o < 4; ++o) {
        float a0 = 0.f, a1 = 0.f, a2 = 0.f, a3 = 0.f;
#pragma unroll
        for (int i = 0; i < 5; ++i) {
            float w = wc[(50 + o * 6 + i) * 42];
            a0 = fmaf(w, h1[0][i], a0);
            a1 = fmaf(w, h1[1][i], a1);
            a2 = fmaf(w, h1[2][i], a2);
            a3 = fmaf(w, h1[3][i], a3);
        }
        float bs = wc[(50 + o * 6 + 5) * 42];
        h2[0][o] = fmaxf(a0 + bs, 0.f);
        h2[1][o] = fmaxf(a1 + bs, 0.f);
        h2[2][o] = fmaxf(a2 + bs, 0.f);
        h2[3][o] = fmaxf(a3 + bs, 0.f);
    }
#pragma unroll
    for (int o = 0; o < 4; ++o) {
        float a0 = 0.f, a1 = 0.f, a2 = 0.f, a3 = 0.f;
#pragma unroll
        for (int i = 0; i < 4; ++i) {
            float w = wc[(74 + o * 5 + i) * 42];
            a0 = fmaf(w, h2[0][i], a0);
            a1 = fmaf(w, h2[1][i], a1);
            a2 = fmaf(w, h2[2][i], a2);
            a3 = fmaf(w, h2[3][i], a3);
        }
        float bs = wc[(74 + o * 5 + 4) * 42];
        h3[0][o] = fmaxf(a0 + bs, 0.f);
        h3[1][o] = fmaxf(a1 + bs, 0.f);
        h3[2][o] = fmaxf(a2 + bs, 0.f);
        h3[3][o] = fmaxf(a3 + bs, 0.f);
    }
#pragma unroll
    for (int o = 0; o < 3; ++o) {
        float a0 = 0.f, a1 = 0.f, a2 = 0.f, a3 = 0.f;
#pragma unroll
        for (int i = 0; i < 4; ++i) {
            float w = wc[(94 + o * 5 + i) * 42];
            a0 = fmaf(w, h3[0][i], a0);
            a1 = fmaf(w, h3[1][i], a1);
            a2 = fmaf(w, h3[2][i], a2);
            a3 = fmaf(w, h3[3][i], a3);
        }
        float bs = wc[(94 + o * 5 + 4) * 42];
        oo[0][o] = a0 + bs; oo[1][o] = a1 + bs; oo[2][o] = a2 + bs; oo[3][o] = a3 + bs;
    }
#pragma unroll
    for (int q = 0; q < 4; ++q) {
        float v0 = oo[q][0], v1 = oo[q][1], v2 = oo[q][2];
        float m = fmaxf(fmaxf(v0, v1), v2);
        float e0 = __expf(v0 - m), e1 = __expf(v1 - m), e2 = __expf(v2 - m);
        float rs = frcp(e0 + e1 + e2);
        int base = 2 * BC + (p0 + q * QS) * 3;
        out[base + 0] = e0 * rs;
        out[base + 1] = e1 * rs;
        out[base + 2] = e2 * rs;
    }
}

extern "C" void kernel_launch(void* const* d_in, const int* in_sizes, int n_in,
                              void* d_out, int out_size, void* d_ws, size_t ws_size,
                              hipStream_t stream) {
    const float* tau  = (const float*)d_in[0];
    const float* mu_d = (const float*)d_in[1];
    const float* mu_f = (const float*)d_in[2];
    const float* cons = (const float*)d_in[3];

    dim3 grid(BC4 / 256);   // 21504 blocks, exact cover
    scat_main<<<grid, 256, 0, stream>>>(
        tau, mu_d, mu_f, cons,
        (const float*)d_in[4],  (const float*)d_in[5],
        (const float*)d_in[6],  (const float*)d_in[7],
        (const float*)d_in[8],  (const float*)d_in[9],
        (const float*)d_in[10], (const float*)d_in[11],
        (const float*)d_in[12], (const float*)d_in[13],
        (const float*)d_in[14], (const float*)d_in[15],
        (const float*)d_in[16], (const float*)d_in[17],
        (const float*)d_in[18], (const float*)d_in[19],
        (float*)d_out);
}